// Round 1
// baseline (35.483 us; speedup 1.0000x reference)
//
#include <hip/hip_runtime.h>
#include <math.h>

#define KK 27
#define MM 4
#define OUTC 32
#define GG 64
#define DILF 0.05f
#define MAXDF 1.0f
#define MU 4e-3f   // ambiguity margin in grid-units (u-space); FP drift bound ~1e-4

// Bit-exact (numpy op order, no FMA contraction, IEEE div) in-bounds test.
static __device__ inline bool exact_inb(float lx, float ly, float lz,
                                        float ox, float oy, float oz,
                                        float tx, float ty, float tz,
                                        float qx, float qy, float qz, float qw,
                                        float sc, float gcs) {
#pragma clang fp contract(off)
    float px = lx + ox, py = ly + oy, pz = lz + oz;
    float vx = px - tx, vy = py - ty, vz = pz - tz;
    float ux = -qx, uy = -qy, uz = -qz;
    // c = cross(u, v)
    float cx = uy * vz - uz * vy;
    float cy = uz * vx - ux * vz;
    float cz = ux * vy - uy * vx;
    // t = c + w*v
    float twx = cx + qw * vx;
    float twy = cy + qw * vy;
    float twz = cz + qw * vz;
    // r = v + 2*cross(u, t)
    float rx = vx + 2.0f * (uy * twz - uz * twy);
    float ry = vy + 2.0f * (uz * twx - ux * twz);
    float rz = vz + 2.0f * (ux * twy - uy * twx);
    rx = rx / sc; ry = ry / sc; rz = rz / sc;
    return (rx >= 0.0f) & (rx <= gcs) & (ry >= 0.0f) & (ry <= gcs) &
           (rz >= 0.0f) & (rz <= gcs);
}

__global__ __launch_bounds__(256) void convsdf_kernel(
    const float* __restrict__ locs, const int* __restrict__ idxs,
    const float* __restrict__ poses, const float* __restrict__ scales,
    const float* __restrict__ sdf, const float* __restrict__ cells,
    const float* __restrict__ weight, const float* __restrict__ bias,
    float* __restrict__ out, int N) {
    __shared__ float4 s_ro[MM][KK];      // rot_inv(off) / (sc*cs)  (u-space offsets)
    __shared__ float4 s_off[KK];         // raw kernel offsets
    __shared__ float4 s_wT4[KK * OUTC / 4];  // weight transposed: wT[k][o]
    __shared__ float  s_bias[OUTC];
    __shared__ float  s_t[MM][3];
    __shared__ float  s_q[MM][4];
    __shared__ float  s_sc[MM];
    __shared__ float  s_gcs[MM];         // G * cs (exact, pow2 mult)
    __shared__ float  s_invscs[MM];      // 1 / (sc * cs)
    __shared__ int    s_goff[MM];

    const int b = blockIdx.y;
    const int tid = threadIdx.x;

    // weight transpose into LDS: wT[k*32+o] = weight[o*27+k]
    float* s_wT = (float*)s_wT4;
    for (int i = tid; i < KK * OUTC; i += 256) {
        int k = i >> 5, o = i & 31;
        s_wT[i] = weight[o * KK + k];
    }
    if (tid < OUTC) s_bias[tid] = bias[tid];
    if (tid < KK) {
        int kx = tid / 9, ky = (tid / 3) % 3, kz = tid % 3;
        s_off[tid] = make_float4((float)(kx - 1) * DILF, (float)(ky - 1) * DILF,
                                 (float)(kz - 1) * DILF, 0.0f);
    }
    if (tid >= 128 && tid < 128 + MM) {
        int m = tid - 128;
        const float* pp = poses + (b * MM + m) * 7;
        float tx = pp[0], ty = pp[1], tz = pp[2];
        float qx = pp[3], qy = pp[4], qz = pp[5], qw = pp[6];
        float sc = scales[b * MM + m];
        int gi = idxs[b * MM + m];
        float cs = cells[gi];
        s_t[m][0] = tx; s_t[m][1] = ty; s_t[m][2] = tz;
        s_q[m][0] = qx; s_q[m][1] = qy; s_q[m][2] = qz; s_q[m][3] = qw;
        s_sc[m] = sc;
        s_gcs[m] = (float)GG * cs;
        s_invscs[m] = 1.0f / (sc * cs);
        s_goff[m] = gi * GG * GG * GG;
    }
    __syncthreads();

    // rotated kernel offsets in u-space (fast path only; any FP order ok)
    if (tid < MM * KK) {
        int m = tid / KK, k = tid - m * KK;
        float4 off = s_off[k];
        float qx = s_q[m][0], qy = s_q[m][1], qz = s_q[m][2], qw = s_q[m][3];
        float ux = -qx, uy = -qy, uz = -qz;
        float vx = off.x, vy = off.y, vz = off.z;
        float cx = uy * vz - uz * vy + qw * vx;
        float cy = uz * vx - ux * vz + qw * vy;
        float cz = ux * vy - uy * vx + qw * vz;
        float rx = vx + 2.0f * (uy * cz - uz * cy);
        float ry = vy + 2.0f * (uz * cx - ux * cz);
        float rz = vz + 2.0f * (ux * cy - uy * cx);
        float f = s_invscs[m];
        s_ro[m][k] = make_float4(rx * f, ry * f, rz * f, 0.0f);
    }
    __syncthreads();

    int n = blockIdx.x * 256 + tid;
    if (n >= N) return;

    const float* lp = locs + (size_t)(b * N + n) * 3;
    float lx = lp[0], ly = lp[1], lz = lp[2];

    // per-model base position in u-space: rot_inv(loc - t) / (sc*cs)
    float bux[MM], buy[MM], buz[MM];
#pragma unroll
    for (int m = 0; m < MM; ++m) {
        float vx = lx - s_t[m][0], vy = ly - s_t[m][1], vz = lz - s_t[m][2];
        float qx = s_q[m][0], qy = s_q[m][1], qz = s_q[m][2], qw = s_q[m][3];
        float ux = -qx, uy = -qy, uz = -qz;
        float cx = uy * vz - uz * vy + qw * vx;
        float cy = uz * vx - ux * vz + qw * vy;
        float cz = ux * vy - uy * vx + qw * vz;
        float rx = vx + 2.0f * (uy * cz - uz * cy);
        float ry = vy + 2.0f * (uz * cx - ux * cz);
        float rz = vz + 2.0f * (ux * cy - uy * cx);
        float f = s_invscs[m];
        bux[m] = rx * f; buy[m] = ry * f; buz[m] = rz * f;
    }

    float acc[OUTC];
#pragma unroll
    for (int o = 0; o < OUTC; ++o) acc[o] = s_bias[o];

#pragma unroll 1
    for (int k = 0; k < KK; ++k) {
        float dk = MAXDF;
#pragma unroll
        for (int m = 0; m < MM; ++m) {
            float4 ro = s_ro[m][k];
            float ux = bux[m] + ro.x;
            float uy = buy[m] + ro.y;
            float uz = buz[m] + ro.z;
            // fast in-bounds: u in [0, 64] on all axes
            float mn = fminf(fminf(ux, uy), uz);
            float mx = fmaxf(fmaxf(ux, uy), uz);
            bool inb = (mn >= 0.0f) & (mx <= 64.0f);
            // ambiguity: any axis within MU of a boundary -> redo exactly
            float a0 = fminf(fminf(fabsf(ux), fabsf(uy)), fabsf(uz));
            float a1 = fminf(fminf(fabsf(ux - 64.0f), fabsf(uy - 64.0f)),
                             fabsf(uz - 64.0f));
            if (fminf(a0, a1) < MU) {
                float4 ofk = s_off[k];
                inb = exact_inb(lx, ly, lz, ofk.x, ofk.y, ofk.z,
                                s_t[m][0], s_t[m][1], s_t[m][2],
                                s_q[m][0], s_q[m][1], s_q[m][2], s_q[m][3],
                                s_sc[m], s_gcs[m]);
            }
            // trilinear sample (continuous in u -> fast-path u is fine)
            float gx = fminf(fmaxf(ux - 0.5f, 0.0f), 63.0f);
            float gy = fminf(fmaxf(uy - 0.5f, 0.0f), 63.0f);
            float gz = fminf(fmaxf(uz - 0.5f, 0.0f), 63.0f);
            int ix = min((int)gx, 62);
            int iy = min((int)gy, 62);
            int iz = min((int)gz, 62);
            float fx = gx - (float)ix;
            float fy = gy - (float)iy;
            float fz = gz - (float)iz;
            const float* g = sdf + s_goff[m] + ((ix * GG + iy) * GG + iz);
            float v000 = g[0], v001 = g[1];
            float v010 = g[GG], v011 = g[GG + 1];
            float v100 = g[GG * GG], v101 = g[GG * GG + 1];
            float v110 = g[GG * GG + GG], v111 = g[GG * GG + GG + 1];
            float c00 = v000 + fz * (v001 - v000);
            float c01 = v010 + fz * (v011 - v010);
            float c10 = v100 + fz * (v101 - v100);
            float c11 = v110 + fz * (v111 - v110);
            float c0 = c00 + fy * (c01 - c00);
            float c1 = c10 + fy * (c11 - c10);
            float v = c0 + fx * (c1 - c0);
            v = inb ? v * s_sc[m] : MAXDF;
            dk = fminf(dk, v);
        }
#pragma unroll
        for (int j = 0; j < OUTC / 4; ++j) {
            float4 w4 = s_wT4[k * (OUTC / 4) + j];
            acc[4 * j + 0] += dk * w4.x;
            acc[4 * j + 1] += dk * w4.y;
            acc[4 * j + 2] += dk * w4.z;
            acc[4 * j + 3] += dk * w4.w;
        }
    }

    float* op = out + (size_t)(b * N + n) * OUTC;
#pragma unroll
    for (int j = 0; j < OUTC / 4; ++j) {
        float4 v;
        v.x = acc[4 * j + 0]; v.y = acc[4 * j + 1];
        v.z = acc[4 * j + 2]; v.w = acc[4 * j + 3];
        *(float4*)&op[4 * j] = v;
    }
}

extern "C" void kernel_launch(void* const* d_in, const int* in_sizes, int n_in,
                              void* d_out, int out_size, void* d_ws, size_t ws_size,
                              hipStream_t stream) {
    const float* locs   = (const float*)d_in[0];
    const int*   idxs   = (const int*)d_in[1];
    const float* poses  = (const float*)d_in[2];
    const float* scales = (const float*)d_in[3];
    const float* sdf    = (const float*)d_in[4];
    const float* cells  = (const float*)d_in[5];
    const float* weight = (const float*)d_in[6];
    const float* bias   = (const float*)d_in[7];
    float* out = (float*)d_out;

    int B = in_sizes[1] / MM;          // idxs is [B, M]
    int N = in_sizes[0] / (3 * B);     // locs is [B, N, 3]

    dim3 grid((N + 255) / 256, B);
    convsdf_kernel<<<grid, 256, 0, stream>>>(locs, idxs, poses, scales, sdf,
                                             cells, weight, bias, out, N);
}